// Round 7
// baseline (526.088 us; speedup 1.0000x reference)
//
#include <hip/hip_runtime.h>
#include <math.h>

// Problem constants
constexpr int BB   = 8;      // mamba batch (2x half-batch)
constexpr int HB   = 4;      // half batch
constexpr int LSEQ = 2048;   // sequence length
constexpr int DMv  = 64;     // d_model
constexpr int DIv  = 128;    // d_inner
constexpr int DSv  = 16;     // d_state
constexpr int DRv  = 4;      // dt rank
constexpr int KCv  = 4;      // conv kernel
constexpr int NPOS = BB * LSEQ;          // 16384 positions
constexpr int CH   = 16;                 // scan chunk length
constexpr int NCH  = LSEQ / CH;          // 128 chunks
constexpr int NLANE = BB * DIv * DSv;    // 16384 scan lanes
constexpr int NROW = CH + 3;             // 19 rows incl. conv halo

#define DEV static __device__ __forceinline__

DEV float fast_rcp(float v) { return __builtin_amdgcn_rcpf(v); }
DEV float siluf(float v) { return v * fast_rcp(1.0f + __expf(-v)); }
// softplus via HW log (v_log_f32), no libcall
DEV float softplusf(float v) { return (v > 20.0f) ? v : __logf(1.0f + __expf(v)); }

// ---------------- weight repack (once per call) ----------------
__global__ void k_transpose(const float* __restrict__ Aa, const float* __restrict__ Ab,
                            int R, int C, float* __restrict__ dst) {
    int z = blockIdx.z;
    const float* src = (z < 2) ? (Aa + (size_t)z * R * C) : (Ab + (size_t)(z - 2) * R * C);
    float* d = dst + (size_t)z * R * C;
    int idx = blockIdx.x * blockDim.x + threadIdx.x;
    if (idx >= R * C) return;
    int r = idx / C, c = idx % C;
    d[c * R + r] = src[idx];
}

// quad-pack: src[e*K + k] -> dst[((k>>2)*E + e)*4 + (k&3)]
__global__ void k_quadpack(const float* __restrict__ Aa, const float* __restrict__ Ab,
                           int E, int K, float* __restrict__ dst) {
    int z = blockIdx.z;
    const float* src = (z < 2) ? (Aa + (size_t)z * E * K) : (Ab + (size_t)(z - 2) * E * K);
    float* d = dst + (size_t)z * E * K;
    int idx = blockIdx.x * blockDim.x + threadIdx.x;
    if (idx >= E * K) return;
    int e = idx / K, k = idx % K;
    d[((size_t)(k >> 2) * E + e) * 4 + (k & 3)] = src[idx];
}

// ================= fused front =================================================
// in-proj(+gather) + conv + x-proj + delta + scan pass 1.
// grid (BB, NCH), block 512 (8 waves). Thread phase-1 role: (col e, k-half kh).
// MODE 0: rows from S1. MODE 1: prep_a gather. MODE 2: prep_b gather.
template<int MODE>
__global__ __launch_bounds__(512, 8) void k_front(
    const float* __restrict__ S1, const float* __restrict__ S2,
    const float* __restrict__ WQ,          // in_w quad-packed [16][256]xfloat4
    const float* __restrict__ conv_w, const float* __restrict__ conv_b,
    const float* __restrict__ XPWT,        // xp_w^T [128][36] (global, L1-resident)
    const float* __restrict__ A_log, const float* __restrict__ dt_w,
    const float* __restrict__ dt_b,
    float* __restrict__ XA_g, float* __restrict__ SZ_g, float* __restrict__ XD_g,
    float* __restrict__ DL_g,
    float* __restrict__ Pc, float* __restrict__ Sc)
{
    // LDS: p1 [19][256] partials / x rows (stride 256); dl aliases p1 (dead after conv)
    __shared__ float smem[NROW * 256 + CH * DIv + CH * 36];
    float* p1 = smem;                          // [19][256]
    float* dl = smem;                          // alias: [16][128] delta
    float* xa = smem + NROW * 256;             // [16][128]
    float* xd = smem + NROW * 256 + CH * DIv;  // [16][36]

    const int t  = threadIdx.x;
    const int b8 = blockIdx.x, ch = blockIdx.y;
    const int c0 = ch * CH;

    // ---- phase 1: in-proj GEMV, k split across 2 halves ----
    {
        const int e  = t & 255;
        const int kh = t >> 8;   // 0/1
        // row pointers (block-uniform)
        const float* rows[NROW];
#pragma unroll
        for (int i = 0; i < NROW; ++i) {
            int c = c0 - 3 + i;
            if (c < 0) { rows[i] = nullptr; continue; }
            if (MODE == 0) {
                rows[i] = S1 + ((size_t)b8 * LSEQ + c) * DMv;
            } else {
                int b = b8 & 3;
                bool first = (MODE == 1) ? (c < (LSEQ / 2)) : ((c & 1) == 0);
                const float* sel;
                if (MODE == 1) sel = (b8 < HB) ? (first ? S1 : S2) : (first ? S2 : S1);
                else           sel = (b8 < HB) ? (first ? S2 : S1) : (first ? S1 : S2);
                rows[i] = sel + ((size_t)b * LSEQ + c) * DMv;
            }
        }
        float acc[NROW];
#pragma unroll
        for (int i = 0; i < NROW; ++i) acc[i] = 0.f;
        const float4* wq4 = (const float4*)WQ;
#pragma unroll
        for (int q = 0; q < 8; ++q) {
            float4 wv = wq4[(kh * 8 + q) * 256 + e];
#pragma unroll
            for (int i = 0; i < NROW; ++i) {
                if (rows[i]) {
                    float4 v = ((const float4*)rows[i])[kh * 8 + q];
                    acc[i] = fmaf(v.x, wv.x, acc[i]);
                    acc[i] = fmaf(v.y, wv.y, acc[i]);
                    acc[i] = fmaf(v.z, wv.z, acc[i]);
                    acc[i] = fmaf(v.w, wv.w, acc[i]);
                }
            }
        }
        if (kh == 1) {
#pragma unroll
            for (int i = 0; i < NROW; ++i) p1[i * 256 + e] = acc[i];
        }
        __syncthreads();
        if (kh == 0) {
#pragma unroll
            for (int i = 0; i < NROW; ++i) {
                float v = acc[i] + p1[i * 256 + e];
                if (e < DIv) p1[i * 256 + e] = v;                       // x-part
                else if (i >= 3)
                    SZ_g[((size_t)b8 * LSEQ + (c0 - 3 + i)) * DIv + (e - DIv)] = siluf(v);
            }
        }
        __syncthreads();
    }

    // ---- phase 2: causal conv (K=4) + silu ----
    for (int f = t; f < CH * DIv; f += 512) {
        int l = f >> 7, d = f & 127;
        float a = conv_b[d];
#pragma unroll
        for (int k = 0; k < KCv; ++k)
            a = fmaf(conv_w[d * KCv + k], p1[(l + k) * 256 + d], a);
        float v = siluf(a);
        xa[f] = v;
        XA_g[((size_t)b8 * LSEQ + c0) * DIv + f] = v;
    }
    __syncthreads();

    // ---- phase 3: x-proj (36 outputs per position), weights from L1 ----
    for (int f = t; f < CH * 36; f += 512) {
        int l = f / 36, e = f % 36;
        const float* x = xa + l * DIv;
        float a0 = 0.f, a1 = 0.f;
#pragma unroll
        for (int k = 0; k < DIv; k += 2) {
            a0 = fmaf(x[k],     XPWT[k * 36 + e],       a0);
            a1 = fmaf(x[k + 1], XPWT[(k + 1) * 36 + e], a1);
        }
        float v = a0 + a1;
        xd[f] = v;
        XD_g[((size_t)b8 * LSEQ + c0) * 36 + f] = v;
    }
    __syncthreads();

    // ---- phase 3b: delta = softplus(dt . dt_w + dt_b), once per (l,d) ----
    for (int f = t; f < CH * DIv; f += 512) {
        int l = f >> 7, d = f & 127;
        const float* xdl = xd + l * 36;
        float a = dt_b[d];
#pragma unroll
        for (int r = 0; r < DRv; ++r) a = fmaf(xdl[r], dt_w[d * DRv + r], a);
        float delta = softplusf(a);
        dl[f] = delta;      // aliases p1 (dead)
        DL_g[((size_t)b8 * LSEQ + c0) * DIv + f] = delta;
    }
    __syncthreads();

    // ---- phase 4: scan pass 1 (thread = (d, s-quarter), 4 states in regs) ----
    {
        int d = t & 127, sg = t >> 7;   // sg 0..3
        float A[4], h[4], P[4];
#pragma unroll
        for (int s = 0; s < 4; ++s) {
            A[s] = -__expf(A_log[d * DSv + sg * 4 + s]);
            h[s] = 0.f; P[s] = 1.f;
        }
        for (int l = 0; l < CH; ++l) {
            float delta = dl[l * DIv + d];
            float dx = delta * xa[l * DIv + d];
            const float* xdl = xd + l * 36;
#pragma unroll
            for (int s = 0; s < 4; ++s) {
                float dA = __expf(delta * A[s]);
                h[s] = fmaf(dA, h[s], dx * xdl[DRv + sg * 4 + s]);
                P[s] *= dA;
            }
        }
        size_t ofs = (size_t)ch * NLANE + ((size_t)b8 * DIv + d) * DSv + sg * 4;
        *(float4*)(Pc + ofs) = make_float4(P[0], P[1], P[2], P[3]);
        *(float4*)(Sc + ofs) = make_float4(h[0], h[1], h[2], h[3]);
    }
}

// Pass 2: serial combine over chunks -> chunk-start states, IN PLACE over Pc.
__global__ void k_scan2(float* PcH0, const float* __restrict__ Sc) {
    int t = blockIdx.x * blockDim.x + threadIdx.x;
    if (t >= NLANE) return;
    float hs = 0.f;
    for (int c = 0; c < NCH; ++c) {
        size_t ix = (size_t)c * NLANE + t;
        float p = PcH0[ix];
        float s = Sc[ix];
        PcH0[ix] = hs;
        hs = fmaf(p, hs, s);
    }
}

// ================= fused back: scan replay + gate + out-proj + residual =========
// grid (HB, NCH), block 256 = two batch halves x 128 d.
template<bool SAVE_CF>
__global__ __launch_bounds__(256) void k_back(
    const float* __restrict__ XA, const float* __restrict__ XD,
    const float* __restrict__ SZ, const float* __restrict__ DL,
    const float* __restrict__ A_log, const float* __restrict__ Dp,
    const float* __restrict__ H0,          // = Pc after k_scan2
    const float* __restrict__ WQ,          // out_w quad-packed [32][64]xfloat4
    const float* __restrict__ RES,
    float* __restrict__ CF, float* __restrict__ OUT)
{
    __shared__ float lds_xd[2 * CH * 36];
    __shared__ float lds_y[2 * CH * DIv];
    const int t  = threadIdx.x;
    const int bq = blockIdx.x, ch = blockIdx.y;

    // stage XD tiles for both batch halves
    for (int f = t; f < 2 * CH * 36; f += 256) {
        int half = f / (CH * 36), r = f % (CH * 36);
        int beff = bq + half * HB;
        lds_xd[f] = XD[((size_t)beff * LSEQ + ch * CH) * 36 + r];
    }
    __syncthreads();

    // ---- scan replay + C-dot + D*x + silu(z) gate ----
    {
        int half = t >> 7, d = t & 127;
        int beff = bq + half * HB;
        float A[DSv];
#pragma unroll
        for (int s = 0; s < DSv; ++s) A[s] = -__expf(A_log[d * DSv + s]);
        float Dd = Dp[d];
        float h[DSv];
        size_t ofs = (size_t)ch * NLANE + ((size_t)beff * DIv + d) * DSv;
        const float4* h4 = (const float4*)(H0 + ofs);
#pragma unroll
        for (int q = 0; q < 4; ++q) {
            float4 v = h4[q];
            h[4 * q] = v.x; h[4 * q + 1] = v.y; h[4 * q + 2] = v.z; h[4 * q + 3] = v.w;
        }
        const float* xdh = lds_xd + half * CH * 36;
        for (int l = 0; l < CH; ++l) {
            const float* xd = xdh + l * 36;
            size_t base = (size_t)beff * LSEQ + ch * CH + l;
            float delta = DL[base * DIv + d];
            float x  = XA[base * DIv + d];
            float dx = delta * x;
            float p = 0.f;
#pragma unroll
            for (int s = 0; s < DSv; ++s) {
                float dA = __expf(delta * A[s]);
                h[s] = fmaf(dA, h[s], dx * xd[DRv + s]);
                p = fmaf(h[s], xd[DRv + DSv + s], p);
            }
            float y = fmaf(Dd, x, p);
            lds_y[half * CH * DIv + l * DIv + d] = y * SZ[base * DIv + d];
        }
    }
    __syncthreads();

    // ---- out-proj + 0.5*(cf1+cf2)+res, relu ----
    {
        int e = t & 63, grp = t >> 6;
        float w[DIv];
        const float4* wq4 = (const float4*)WQ;
#pragma unroll
        for (int q = 0; q < DIv / 4; ++q) {
            float4 v = wq4[q * 64 + e];
            w[4 * q] = v.x; w[4 * q + 1] = v.y; w[4 * q + 2] = v.z; w[4 * q + 3] = v.w;
        }
#pragma unroll
        for (int i = 0; i < 4; ++i) {
            int l = grp * 4 + i;
            const float* y1 = lds_y + l * DIv;
            const float* y2 = lds_y + CH * DIv + l * DIv;
            float a1 = 0.f, b1 = 0.f, a2 = 0.f, b2 = 0.f;
#pragma unroll
            for (int k = 0; k < DIv; k += 2) {
                a1 = fmaf(y1[k],     w[k],     a1);
                b1 = fmaf(y1[k + 1], w[k + 1], b1);
                a2 = fmaf(y2[k],     w[k],     a2);
                b2 = fmaf(y2[k + 1], w[k + 1], b2);
            }
            float c1 = a1 + b1, c2 = a2 + b2;
            size_t pos1 = (size_t)bq * LSEQ + ch * CH + l;
            size_t pos2 = pos1 + (size_t)HB * LSEQ;
            if (SAVE_CF) {
                CF[pos1 * DMv + e] = c1;
                CF[pos2 * DMv + e] = c2;
            }
            float v = fmaf(0.5f, c1 + c2, RES[pos1 * DMv + e]);
            OUT[pos1 * DMv + e] = fmaxf(v, 0.f);
        }
    }
}

extern "C" void kernel_launch(void* const* d_in, const int* in_sizes, int n_in,
                              void* d_out, int out_size, void* d_ws, size_t ws_size,
                              hipStream_t stream) {
    const float* Ms_in  = (const float*)d_in[0];
    const float* Pan_in = (const float*)d_in[1];
    const float* pa[9];
    const float* pb[9];
    for (int i = 0; i < 9; ++i) {
        pa[i] = (const float*)d_in[2 + i];
        pb[i] = (const float*)d_in[11 + i];
    }
    float* out    = (float*)d_out;
    float* OutMs  = out;
    float* OutPan = out + (size_t)HB * LSEQ * DMv;

    float* ws = (float*)d_ws;
    size_t o = 0;
    float* CF = ws + o; o += (size_t)NPOS * DMv;        // raw mamba out (layer0)
    float* XA = ws + o; o += (size_t)NPOS * DIv;        // conv+silu x
    float* SZ = ws + o; o += (size_t)NPOS * DIv;        // silu(z)
    float* XD = ws + o; o += (size_t)NPOS * 36;         // dt|B|C
    float* DL = ws + o; o += (size_t)NPOS * DIv;        // delta
    float* Pc = ws + o; o += (size_t)NCH * NLANE;       // chunk products -> H0
    float* Sc = ws + o; o += (size_t)NCH * NLANE;       // chunk local scans
    float* W2Q  = ws + o; o += (size_t)4 * DMv * 2 * DIv;   // in_w quad-packed
    float* XPWT = ws + o; o += (size_t)4 * DIv * 36;        // xp_w^T
    float* OUTQ = ws + o; o += (size_t)4 * DIv * DMv;       // out_w quad-packed

    const int TB = 256;

    // ---- one-time weight repacks (z = path*2 + layer) ----
    {
        dim3 gt1((2 * DIv * DMv + TB - 1) / TB, 1, 4);
        k_quadpack<<<gt1, TB, 0, stream>>>(pa[0], pb[0], 2 * DIv, DMv, W2Q);
        dim3 gt2((36 * DIv + TB - 1) / TB, 1, 4);
        k_transpose<<<gt2, TB, 0, stream>>>(pa[3], pb[3], 36, DIv, XPWT);
        dim3 gt3((DMv * DIv + TB - 1) / TB, 1, 4);
        k_quadpack<<<gt3, TB, 0, stream>>>(pa[8], pb[8], DMv, DIv, OUTQ);
    }

    dim3 gF(BB, NCH);
    dim3 gB(HB, NCH);
    int gS = (NLANE + TB - 1) / TB;

    auto scan_mid = [&]() { k_scan2<<<gS, TB, 0, stream>>>(Pc, Sc); };

    auto cw  = [&](const float* const* P, int L) { return P[1] + (size_t)L * DIv * KCv; };
    auto cb  = [&](const float* const* P, int L) { return P[2] + (size_t)L * DIv; };
    auto dw  = [&](const float* const* P, int L) { return P[4] + (size_t)L * DIv * DRv; };
    auto db  = [&](const float* const* P, int L) { return P[5] + (size_t)L * DIv; };
    auto al  = [&](const float* const* P, int L) { return P[6] + (size_t)L * DIv * DSv; };
    auto dp  = [&](const float* const* P, int L) { return P[7] + (size_t)L * DIv; };

    // ---- path a (updates Ms); z = 0,1 ----
    k_front<1><<<gF, 512, 0, stream>>>(Ms_in, Pan_in, W2Q + (size_t)0 * DMv * 2 * DIv,
                                       cw(pa,0), cb(pa,0), XPWT + (size_t)0 * DIv * 36,
                                       al(pa,0), dw(pa,0), db(pa,0), XA, SZ, XD, DL, Pc, Sc);
    scan_mid();
    k_back<true><<<gB, 256, 0, stream>>>(XA, XD, SZ, DL, al(pa,0), dp(pa,0),
                                         Pc, OUTQ + (size_t)0 * DIv * DMv, Ms_in, CF, OutMs);

    k_front<0><<<gF, 512, 0, stream>>>(CF, nullptr, W2Q + (size_t)1 * DMv * 2 * DIv,
                                       cw(pa,1), cb(pa,1), XPWT + (size_t)1 * DIv * 36,
                                       al(pa,1), dw(pa,1), db(pa,1), XA, SZ, XD, DL, Pc, Sc);
    scan_mid();
    k_back<false><<<gB, 256, 0, stream>>>(XA, XD, SZ, DL, al(pa,1), dp(pa,1),
                                          Pc, OUTQ + (size_t)1 * DIv * DMv, OutMs, nullptr, OutMs);

    // ---- path b (updates Pan); z = 2,3 ----
    k_front<2><<<gF, 512, 0, stream>>>(OutMs, Pan_in, W2Q + (size_t)2 * DMv * 2 * DIv,
                                       cw(pb,0), cb(pb,0), XPWT + (size_t)2 * DIv * 36,
                                       al(pb,0), dw(pb,0), db(pb,0), XA, SZ, XD, DL, Pc, Sc);
    scan_mid();
    k_back<true><<<gB, 256, 0, stream>>>(XA, XD, SZ, DL, al(pb,0), dp(pb,0),
                                         Pc, OUTQ + (size_t)2 * DIv * DMv, Pan_in, CF, OutPan);

    k_front<0><<<gF, 512, 0, stream>>>(CF, nullptr, W2Q + (size_t)3 * DMv * 2 * DIv,
                                       cw(pb,1), cb(pb,1), XPWT + (size_t)3 * DIv * 36,
                                       al(pb,1), dw(pb,1), db(pb,1), XA, SZ, XD, DL, Pc, Sc);
    scan_mid();
    k_back<false><<<gB, 256, 0, stream>>>(XA, XD, SZ, DL, al(pb,1), dp(pb,1),
                                          Pc, OUTQ + (size_t)3 * DIv * DMv, OutPan, nullptr, OutPan);
}

// Round 8
// 368.747 us; speedup vs baseline: 1.4267x; 1.4267x over previous
//
#include <hip/hip_runtime.h>
#include <math.h>

// Problem constants
constexpr int BB   = 8;      // mamba batch (2x half-batch)
constexpr int HB   = 4;      // half batch
constexpr int LSEQ = 2048;   // sequence length
constexpr int DMv  = 64;     // d_model
constexpr int DIv  = 128;    // d_inner
constexpr int DSv  = 16;     // d_state
constexpr int DRv  = 4;      // dt rank
constexpr int KCv  = 4;      // conv kernel
constexpr int NPOS = BB * LSEQ;          // 16384 positions
constexpr int CH   = 16;                 // scan chunk length
constexpr int NCH  = LSEQ / CH;          // 128 chunks
constexpr int NLANE = BB * DIv * DSv;    // 16384 scan lanes
constexpr int NROW = CH + 3;             // 19 rows incl. conv halo

#define DEV static __device__ __forceinline__

DEV float fast_rcp(float v) { return __builtin_amdgcn_rcpf(v); }
DEV float siluf(float v) { return v * fast_rcp(1.0f + __expf(-v)); }
DEV float softplusf(float v) { return (v > 20.0f) ? v : __logf(1.0f + __expf(v)); }

// ---------------- weight repack (once per call) ----------------
__global__ void k_transpose(const float* __restrict__ Aa, const float* __restrict__ Ab,
                            int R, int C, float* __restrict__ dst) {
    int z = blockIdx.z;
    const float* src = (z < 2) ? (Aa + (size_t)z * R * C) : (Ab + (size_t)(z - 2) * R * C);
    float* d = dst + (size_t)z * R * C;
    int idx = blockIdx.x * blockDim.x + threadIdx.x;
    if (idx >= R * C) return;
    int r = idx / C, c = idx % C;
    d[c * R + r] = src[idx];
}

// quad-pack: src[e*K + k] -> dst[((k>>2)*E + e)*4 + (k&3)]
__global__ void k_quadpack(const float* __restrict__ Aa, const float* __restrict__ Ab,
                           int E, int K, float* __restrict__ dst) {
    int z = blockIdx.z;
    const float* src = (z < 2) ? (Aa + (size_t)z * E * K) : (Ab + (size_t)(z - 2) * E * K);
    float* d = dst + (size_t)z * E * K;
    int idx = blockIdx.x * blockDim.x + threadIdx.x;
    if (idx >= E * K) return;
    int e = idx / K, k = idx % K;
    d[((size_t)(k >> 2) * E + e) * 4 + (k & 3)] = src[idx];
}

// ================= fused front =================================================
// in-proj(+gather) + conv + x-proj + scan pass 1. grid (BB, NCH), block 256.
// MODE 0: rows from S1. MODE 1: prep_a gather. MODE 2: prep_b gather.
template<int MODE>
__global__ __launch_bounds__(256, 8) void k_front(
    const float* __restrict__ S1, const float* __restrict__ S2,
    const float* __restrict__ WQ,          // in_w quad-packed [16][256]xfloat4
    const float* __restrict__ conv_w, const float* __restrict__ conv_b,
    const float* __restrict__ XPWT,        // xp_w^T [128][36]
    const float* __restrict__ A_log, const float* __restrict__ dt_w,
    const float* __restrict__ dt_b,
    float* __restrict__ XA_g, float* __restrict__ SZ_g, float* __restrict__ XD_g,
    float* __restrict__ Pc, float* __restrict__ Sc)
{
    // LDS: lds_x [19][128] (x rows; later xa [16][128]); lds_xd [16][36];
    //      lds_w [128][36] (= phase-1 scratch: scrA [19][128], scrB [16][128])
    __shared__ float smem[NROW * 128 + CH * 36 + DIv * 36];
    float* lds_x  = smem;
    float* lds_xd = smem + NROW * 128;
    float* lds_w  = smem + NROW * 128 + CH * 36;
    float* scrA   = lds_w;                 // [19][128]
    float* scrB   = lds_w + NROW * 128;    // [16][128]  (4608-2432=2176 >= 2048 ok)

    const int t  = threadIdx.x;
    const int b8 = blockIdx.x, ch = blockIdx.y;
    const int c0 = ch * CH;
    const int e2 = t & 127, kh = t >> 7;   // column-in-half, k-half (wave-uniform)
    const float4* wq4 = (const float4*)WQ;

    auto rowptr = [&](int c) -> const float* {
        if (MODE == 0) return S1 + ((size_t)b8 * LSEQ + c) * DMv;
        int b = b8 & 3;
        bool first = (MODE == 1) ? (c < (LSEQ / 2)) : ((c & 1) == 0);
        const float* sel;
        if (MODE == 1) sel = (b8 < HB) ? (first ? S1 : S2) : (first ? S2 : S1);
        else           sel = (b8 < HB) ? (first ? S2 : S1) : (first ? S1 : S2);
        return sel + ((size_t)b * LSEQ + c) * DMv;
    };

    // ---- phase 1 pass A: x columns (0..127), k split across 2 halves ----
    {
        float4 w4[8];
#pragma unroll
        for (int q = 0; q < 8; ++q) w4[q] = wq4[(kh * 8 + q) * 256 + e2];
#pragma unroll
        for (int i = 0; i < NROW; ++i) {
            int c = c0 - 3 + i;
            float a0 = 0.f, a1 = 0.f;
            if (c >= 0) {
                const float4* r4 = (const float4*)rowptr(c) + kh * 8;
#pragma unroll
                for (int q = 0; q < 8; q += 2) {
                    float4 v0 = r4[q], v1 = r4[q + 1];
                    a0 = fmaf(v0.x, w4[q].x, a0);     a0 = fmaf(v0.y, w4[q].y, a0);
                    a0 = fmaf(v0.z, w4[q].z, a0);     a0 = fmaf(v0.w, w4[q].w, a0);
                    a1 = fmaf(v1.x, w4[q + 1].x, a1); a1 = fmaf(v1.y, w4[q + 1].y, a1);
                    a1 = fmaf(v1.z, w4[q + 1].z, a1); a1 = fmaf(v1.w, w4[q + 1].w, a1);
                }
            }
            float a = a0 + a1;
            if (kh == 0) lds_x[i * 128 + e2] = a;
            else         scrA [i * 128 + e2] = a;
        }
    }
    __syncthreads();
    // combine partials for x
    for (int f = t; f < NROW * 128; f += 256) lds_x[f] += scrA[f];
    __syncthreads();

    // ---- phase 1 pass B: z columns (128..255) ----
    {
        float4 w4[8];
#pragma unroll
        for (int q = 0; q < 8; ++q) w4[q] = wq4[(kh * 8 + q) * 256 + 128 + e2];
#pragma unroll
        for (int i = 0; i < CH; ++i) {
            int c = c0 + i;
            const float4* r4 = (const float4*)rowptr(c) + kh * 8;
            float a0 = 0.f, a1 = 0.f;
#pragma unroll
            for (int q = 0; q < 8; q += 2) {
                float4 v0 = r4[q], v1 = r4[q + 1];
                a0 = fmaf(v0.x, w4[q].x, a0);     a0 = fmaf(v0.y, w4[q].y, a0);
                a0 = fmaf(v0.z, w4[q].z, a0);     a0 = fmaf(v0.w, w4[q].w, a0);
                a1 = fmaf(v1.x, w4[q + 1].x, a1); a1 = fmaf(v1.y, w4[q + 1].y, a1);
                a1 = fmaf(v1.z, w4[q + 1].z, a1); a1 = fmaf(v1.w, w4[q + 1].w, a1);
            }
            float a = a0 + a1;
            if (kh == 0) scrA[i * 128 + e2] = a;
            else         scrB[i * 128 + e2] = a;
        }
    }
    __syncthreads();
    // combine + silu -> SZ
    for (int f = t; f < CH * 128; f += 256) {
        float z = scrA[f] + scrB[f];
        SZ_g[((size_t)b8 * LSEQ + c0 + (f >> 7)) * DIv + (f & 127)] = siluf(z);
    }
    __syncthreads();   // scratch (lds_w region) now dead -> stage real weights

    // ---- stage xp_w^T into LDS, and conv into regs (phase 2a) ----
    for (int f = t; f < DIv * 36; f += 256) lds_w[f] = XPWT[f];
    float xar[8];
    {
        const int d = t & 127;
        const int lb = t >> 7;
        float4 cw4 = ((const float4*)conv_w)[d];
        float cb = conv_b[d];
#pragma unroll
        for (int j = 0; j < 8; ++j) {
            int l = lb + 2 * j;
            float a = cb;
            a = fmaf(cw4.x, lds_x[(l + 0) * 128 + d], a);
            a = fmaf(cw4.y, lds_x[(l + 1) * 128 + d], a);
            a = fmaf(cw4.z, lds_x[(l + 2) * 128 + d], a);
            a = fmaf(cw4.w, lds_x[(l + 3) * 128 + d], a);
            float v = siluf(a);
            xar[j] = v;
            XA_g[((size_t)b8 * LSEQ + c0 + l) * DIv + d] = v;
        }
    }
    __syncthreads();
    // phase 2b: write xa into lds_x rows 0..15 (x rows dead now)
    {
        const int d = t & 127;
        const int lb = t >> 7;
#pragma unroll
        for (int j = 0; j < 8; ++j) lds_x[(lb + 2 * j) * 128 + d] = xar[j];
    }
    __syncthreads();

    // ---- phase 3: x-proj (36 outputs per position) ----
    for (int f = t; f < CH * 36; f += 256) {
        int l = f / 36, e = f % 36;
        const float* x = lds_x + l * 128;
        float a0 = 0.f, a1 = 0.f;
#pragma unroll
        for (int k = 0; k < DIv; k += 2) {
            a0 = fmaf(x[k],     lds_w[k * 36 + e],       a0);
            a1 = fmaf(x[k + 1], lds_w[(k + 1) * 36 + e], a1);
        }
        float v = a0 + a1;
        lds_xd[f] = v;
        XD_g[((size_t)b8 * LSEQ + c0) * 36 + f] = v;
    }
    __syncthreads();

    // ---- phase 4: scan pass 1 (thread = (d, s-half), 8 states in regs) ----
    {
        int d = t & 127, sh = t >> 7;
        float A[8], h[8], P[8];
#pragma unroll
        for (int s = 0; s < 8; ++s) {
            A[s] = -__expf(A_log[d * DSv + sh * 8 + s]);
            h[s] = 0.f; P[s] = 1.f;
        }
        float4 dw4 = ((const float4*)dt_w)[d];
        float bb = dt_b[d];
        for (int l = 0; l < CH; ++l) {
            const float* xd = lds_xd + l * 36;
            float delta = softplusf(fmaf(xd[0], dw4.x, fmaf(xd[1], dw4.y,
                                   fmaf(xd[2], dw4.z, fmaf(xd[3], dw4.w, bb)))));
            float dx = delta * lds_x[l * 128 + d];
#pragma unroll
            for (int s = 0; s < 8; ++s) {
                float dA = __expf(delta * A[s]);
                h[s] = fmaf(dA, h[s], dx * xd[DRv + sh * 8 + s]);
                P[s] *= dA;
            }
        }
        size_t ofs = (size_t)ch * NLANE + ((size_t)b8 * DIv + d) * DSv + sh * 8;
        float4* p4 = (float4*)(Pc + ofs);
        float4* s4 = (float4*)(Sc + ofs);
        p4[0] = make_float4(P[0], P[1], P[2], P[3]);
        p4[1] = make_float4(P[4], P[5], P[6], P[7]);
        s4[0] = make_float4(h[0], h[1], h[2], h[3]);
        s4[1] = make_float4(h[4], h[5], h[6], h[7]);
    }
}

// Pass 2: serial combine over chunks -> chunk-start states, IN PLACE over Pc.
__global__ void k_scan2(float* PcH0, const float* __restrict__ Sc) {
    int t = blockIdx.x * blockDim.x + threadIdx.x;
    if (t >= NLANE) return;
    float hs = 0.f;
    for (int c = 0; c < NCH; ++c) {
        size_t ix = (size_t)c * NLANE + t;
        float p = PcH0[ix];
        float s = Sc[ix];
        PcH0[ix] = hs;
        hs = fmaf(p, hs, s);
    }
}

// ================= fused back: scan replay + gate + out-proj + residual =========
// grid (HB, NCH), block 256 = two batch halves x 128 d.
template<bool SAVE_CF>
__global__ __launch_bounds__(256, 8) void k_back(
    const float* __restrict__ XA, const float* __restrict__ XD,
    const float* __restrict__ SZ,
    const float* __restrict__ A_log, const float* __restrict__ dt_w,
    const float* __restrict__ dt_b, const float* __restrict__ Dp,
    const float* __restrict__ H0,          // = Pc after k_scan2
    const float* __restrict__ WQ,          // out_w quad-packed [32][64]xfloat4
    const float* __restrict__ RES,
    float* __restrict__ CF, float* __restrict__ OUT)
{
    __shared__ float lds_xd[2 * CH * 36];
    __shared__ float lds_y[2 * CH * DIv];
    const int t  = threadIdx.x;
    const int bq = blockIdx.x, ch = blockIdx.y;

    for (int f = t; f < 2 * CH * 36; f += 256) {
        int half = f / (CH * 36), r = f % (CH * 36);
        int beff = bq + half * HB;
        lds_xd[f] = XD[((size_t)beff * LSEQ + ch * CH) * 36 + r];
    }
    __syncthreads();

    // ---- scan replay + C-dot + D*x + silu(z) gate ----
    {
        int half = t >> 7, d = t & 127;
        int beff = bq + half * HB;
        float A[DSv];
#pragma unroll
        for (int s = 0; s < DSv; ++s) A[s] = -__expf(A_log[d * DSv + s]);
        float4 dw4 = ((const float4*)dt_w)[d];
        float bb = dt_b[d];
        float Dd = Dp[d];
        float h[DSv];
        size_t ofs = (size_t)ch * NLANE + ((size_t)beff * DIv + d) * DSv;
        const float4* h4 = (const float4*)(H0 + ofs);
#pragma unroll
        for (int q = 0; q < 4; ++q) {
            float4 v = h4[q];
            h[4 * q] = v.x; h[4 * q + 1] = v.y; h[4 * q + 2] = v.z; h[4 * q + 3] = v.w;
        }
        const float* xdh = lds_xd + half * CH * 36;
        for (int l = 0; l < CH; ++l) {
            const float* xd = xdh + l * 36;
            float delta = softplusf(fmaf(xd[0], dw4.x, fmaf(xd[1], dw4.y,
                                   fmaf(xd[2], dw4.z, fmaf(xd[3], dw4.w, bb)))));
            size_t base = (size_t)beff * LSEQ + ch * CH + l;
            float x  = XA[base * DIv + d];
            float dx = delta * x;
            float p = 0.f;
#pragma unroll
            for (int s = 0; s < DSv; ++s) {
                float dA = __expf(delta * A[s]);
                h[s] = fmaf(dA, h[s], dx * xd[DRv + s]);
                p = fmaf(h[s], xd[DRv + DSv + s], p);
            }
            float y = fmaf(Dd, x, p);
            lds_y[half * CH * DIv + l * DIv + d] = y * SZ[base * DIv + d];
        }
    }
    __syncthreads();

    // ---- out-proj (q-outer, wq in 4 regs) + 0.5*(cf1+cf2)+res, relu ----
    {
        int e = t & 63, g = t >> 6;     // g = l-group (wave-uniform)
        int l0 = g * 4;
        const float4* wq4 = (const float4*)WQ;
        float accA[4] = {0.f, 0.f, 0.f, 0.f};
        float accB[4] = {0.f, 0.f, 0.f, 0.f};
#pragma unroll
        for (int q = 0; q < DIv / 4; ++q) {
            float4 wq = wq4[q * 64 + e];
#pragma unroll
            for (int i = 0; i < 4; ++i) {
                const float4 y1 = *(const float4*)(lds_y + (l0 + i) * DIv + q * 4);
                const float4 y2 = *(const float4*)(lds_y + CH * DIv + (l0 + i) * DIv + q * 4);
                accA[i] = fmaf(y1.x, wq.x, accA[i]); accA[i] = fmaf(y1.y, wq.y, accA[i]);
                accA[i] = fmaf(y1.z, wq.z, accA[i]); accA[i] = fmaf(y1.w, wq.w, accA[i]);
                accB[i] = fmaf(y2.x, wq.x, accB[i]); accB[i] = fmaf(y2.y, wq.y, accB[i]);
                accB[i] = fmaf(y2.z, wq.z, accB[i]); accB[i] = fmaf(y2.w, wq.w, accB[i]);
            }
        }
#pragma unroll
        for (int i = 0; i < 4; ++i) {
            size_t pos1 = (size_t)bq * LSEQ + ch * CH + l0 + i;
            size_t pos2 = pos1 + (size_t)HB * LSEQ;
            if (SAVE_CF) {
                CF[pos1 * DMv + e] = accA[i];
                CF[pos2 * DMv + e] = accB[i];
            }
            float v = fmaf(0.5f, accA[i] + accB[i], RES[pos1 * DMv + e]);
            OUT[pos1 * DMv + e] = fmaxf(v, 0.f);
        }
    }
}

extern "C" void kernel_launch(void* const* d_in, const int* in_sizes, int n_in,
                              void* d_out, int out_size, void* d_ws, size_t ws_size,
                              hipStream_t stream) {
    const float* Ms_in  = (const float*)d_in[0];
    const float* Pan_in = (const float*)d_in[1];
    const float* pa[9];
    const float* pb[9];
    for (int i = 0; i < 9; ++i) {
        pa[i] = (const float*)d_in[2 + i];
        pb[i] = (const float*)d_in[11 + i];
    }
    float* out    = (float*)d_out;
    float* OutMs  = out;
    float* OutPan = out + (size_t)HB * LSEQ * DMv;

    float* ws = (float*)d_ws;
    size_t o = 0;
    float* CF = ws + o; o += (size_t)NPOS * DMv;
    float* XA = ws + o; o += (size_t)NPOS * DIv;
    float* SZ = ws + o; o += (size_t)NPOS * DIv;
    float* XD = ws + o; o += (size_t)NPOS * 36;
    float* Pc = ws + o; o += (size_t)NCH * NLANE;
    float* Sc = ws + o; o += (size_t)NCH * NLANE;
    float* W2Q  = ws + o; o += (size_t)4 * DMv * 2 * DIv;
    float* XPWT = ws + o; o += (size_t)4 * DIv * 36;
    float* OUTQ = ws + o; o += (size_t)4 * DIv * DMv;

    const int TB = 256;

    // ---- one-time weight repacks (z = path*2 + layer) ----
    {
        dim3 gt1((2 * DIv * DMv + TB - 1) / TB, 1, 4);
        k_quadpack<<<gt1, TB, 0, stream>>>(pa[0], pb[0], 2 * DIv, DMv, W2Q);
        dim3 gt2((36 * DIv + TB - 1) / TB, 1, 4);
        k_transpose<<<gt2, TB, 0, stream>>>(pa[3], pb[3], 36, DIv, XPWT);
        dim3 gt3((DMv * DIv + TB - 1) / TB, 1, 4);
        k_quadpack<<<gt3, TB, 0, stream>>>(pa[8], pb[8], DMv, DIv, OUTQ);
    }

    dim3 gF(BB, NCH);
    dim3 gB(HB, NCH);
    int gS = (NLANE + TB - 1) / TB;

    auto scan_mid = [&]() { k_scan2<<<gS, TB, 0, stream>>>(Pc, Sc); };

    auto cw  = [&](const float* const* P, int L) { return P[1] + (size_t)L * DIv * KCv; };
    auto cb  = [&](const float* const* P, int L) { return P[2] + (size_t)L * DIv; };
    auto dw  = [&](const float* const* P, int L) { return P[4] + (size_t)L * DIv * DRv; };
    auto db  = [&](const float* const* P, int L) { return P[5] + (size_t)L * DIv; };
    auto al  = [&](const float* const* P, int L) { return P[6] + (size_t)L * DIv * DSv; };
    auto dp  = [&](const float* const* P, int L) { return P[7] + (size_t)L * DIv; };

    // ---- path a (updates Ms); z = 0,1 ----
    k_front<1><<<gF, 256, 0, stream>>>(Ms_in, Pan_in, W2Q + (size_t)0 * DMv * 2 * DIv,
                                       cw(pa,0), cb(pa,0), XPWT + (size_t)0 * DIv * 36,
                                       al(pa,0), dw(pa,0), db(pa,0), XA, SZ, XD, Pc, Sc);
    scan_mid();
    k_back<true><<<gB, 256, 0, stream>>>(XA, XD, SZ, al(pa,0), dw(pa,0), db(pa,0), dp(pa,0),
                                         Pc, OUTQ + (size_t)0 * DIv * DMv, Ms_in, CF, OutMs);

    k_front<0><<<gF, 256, 0, stream>>>(CF, nullptr, W2Q + (size_t)1 * DMv * 2 * DIv,
                                       cw(pa,1), cb(pa,1), XPWT + (size_t)1 * DIv * 36,
                                       al(pa,1), dw(pa,1), db(pa,1), XA, SZ, XD, Pc, Sc);
    scan_mid();
    k_back<false><<<gB, 256, 0, stream>>>(XA, XD, SZ, al(pa,1), dw(pa,1), db(pa,1), dp(pa,1),
                                          Pc, OUTQ + (size_t)1 * DIv * DMv, OutMs, nullptr, OutMs);

    // ---- path b (updates Pan); z = 2,3 ----
    k_front<2><<<gF, 256, 0, stream>>>(OutMs, Pan_in, W2Q + (size_t)2 * DMv * 2 * DIv,
                                       cw(pb,0), cb(pb,0), XPWT + (size_t)2 * DIv * 36,
                                       al(pb,0), dw(pb,0), db(pb,0), XA, SZ, XD, Pc, Sc);
    scan_mid();
    k_back<true><<<gB, 256, 0, stream>>>(XA, XD, SZ, al(pb,0), dw(pb,0), db(pb,0), dp(pb,0),
                                         Pc, OUTQ + (size_t)2 * DIv * DMv, Pan_in, CF, OutPan);

    k_front<0><<<gF, 256, 0, stream>>>(CF, nullptr, W2Q + (size_t)3 * DMv * 2 * DIv,
                                       cw(pb,1), cb(pb,1), XPWT + (size_t)3 * DIv * 36,
                                       al(pb,1), dw(pb,1), db(pb,1), XA, SZ, XD, Pc, Sc);
    scan_mid();
    k_back<false><<<gB, 256, 0, stream>>>(XA, XD, SZ, al(pb,1), dw(pb,1), db(pb,1), dp(pb,1),
                                          Pc, OUTQ + (size_t)3 * DIv * DMv, OutPan, nullptr, OutPan);
}